// Round 12
// baseline (381.593 us; speedup 1.0000x reference)
//
#include <hip/hip_runtime.h>
#include <hip/hip_bf16.h>

#define NEG_INF -1e20f

typedef __bf16 bf16x8 __attribute__((ext_vector_type(8)));
typedef float  f32x4  __attribute__((ext_vector_type(4)));

__device__ inline unsigned short f2bf(float x) {            // RNE, no NaN inputs
    unsigned u = __float_as_uint(x);
    unsigned r = u + 0x7fffu + ((u >> 16) & 1u);
    return (unsigned short)(r >> 16);
}
__device__ inline float bf2f(unsigned short h) {
    return __uint_as_float((unsigned)h << 16);
}
__device__ inline unsigned fkey(float f) {
    unsigned u = __float_as_uint(f);
    return (u & 0x80000000u) ? ~u : (u | 0x80000000u);
}

// ---------------------------------------------------------------------------
// K0: split ctx AND W into 3 bf16 planes each, one launch. VERBATIM R9.
// ---------------------------------------------------------------------------
__global__ __launch_bounds__(256) void split3_all(
        const float* __restrict__ ctx, const float* __restrict__ W,
        unsigned short* __restrict__ C1, unsigned short* __restrict__ C2,
        unsigned short* __restrict__ C3, unsigned short* __restrict__ W1,
        unsigned short* __restrict__ W2, unsigned short* __restrict__ W3) {
    const int b = blockIdx.x;
    const int t = threadIdx.x;
    const float* src;
    unsigned short *p1, *p2, *p3;
    int base;
    if (b < 2048) { src = ctx; p1 = C1; p2 = C2; p3 = C3; base = b * 1024; }
    else          { src = W;   p1 = W1; p2 = W2; p3 = W3; base = (b - 2048) * 1024; }
#pragma unroll
    for (int it = 0; it < 4; ++it) {
        int i = base + it * 256 + t;
        float4 v = ((const float4*)src)[i];
        ushort4 a, bb, c;
        float r;
        a.x = f2bf(v.x); r = v.x - bf2f(a.x); bb.x = f2bf(r); c.x = f2bf(r - bf2f(bb.x));
        a.y = f2bf(v.y); r = v.y - bf2f(a.y); bb.y = f2bf(r); c.y = f2bf(r - bf2f(bb.y));
        a.z = f2bf(v.z); r = v.z - bf2f(a.z); bb.z = f2bf(r); c.z = f2bf(r - bf2f(bb.z));
        a.w = f2bf(v.w); r = v.w - bf2f(a.w); bb.w = f2bf(r); c.w = f2bf(r - bf2f(bb.w));
        ((ushort4*)p1)[i] = a;
        ((ushort4*)p2)[i] = bb;
        ((ushort4*)p3)[i] = c;
    }
}

// ---------------------------------------------------------------------------
// K1: ctx_fc = relu(context @ W^T) via 6-term bf16 MFMA, 128x128 tile,
// 16x16x32 shape. VERBATIM R9/R11.
// ---------------------------------------------------------------------------
__global__ __launch_bounds__(256, 2) void fc_mfma6(
        const unsigned short* __restrict__ A1, const unsigned short* __restrict__ A2,
        const unsigned short* __restrict__ A3, const unsigned short* __restrict__ B1,
        const unsigned short* __restrict__ B2, const unsigned short* __restrict__ B3,
        unsigned short* __restrict__ Fhi, unsigned short* __restrict__ Flo) {
    __shared__ char lds[49152];

    const int t     = threadIdx.x;
    const int mBase = blockIdx.x * 128;   // ctx-row tile
    const int hBase = blockIdx.y * 128;   // W-row (output col) tile
    const int w = t >> 6, lane = t & 63;
    const int q = lane >> 4, ln = lane & 15;
    const int wn = (w >> 1) * 64;
    const int wm = (w & 1) * 64;

    f32x4 acc[4][4] = {};

    for (int kt = 0; kt < 512; kt += 32) {
#pragma unroll
        for (int p = 0; p < 3; ++p) {
            const unsigned short* pl = (p == 0) ? A1 : (p == 1) ? A2 : A3;
#pragma unroll
            for (int rr = 0; rr < 2; ++rr) {
                int chunk = rr * 256 + t;
                int row   = chunk >> 2;
                int c     = (chunk & 3) ^ ((row >> 1) & 3);
                const unsigned short* g = pl + ((size_t)(mBase + row) * 512 + kt + c * 8);
                char* l = lds + p * 8192 + chunk * 16;
                __builtin_amdgcn_global_load_lds(
                    (const __attribute__((address_space(1))) void*)g,
                    (__attribute__((address_space(3))) void*)l, 16, 0, 0);
            }
        }
#pragma unroll
        for (int p = 0; p < 3; ++p) {
            const unsigned short* pl = (p == 0) ? B1 : (p == 1) ? B2 : B3;
#pragma unroll
            for (int rr = 0; rr < 2; ++rr) {
                int chunk = rr * 256 + t;
                int row   = chunk >> 2;
                int c     = (chunk & 3) ^ ((row >> 1) & 3);
                const unsigned short* g = pl + ((size_t)(hBase + row) * 512 + kt + c * 8);
                char* l = lds + 24576 + p * 8192 + chunk * 16;
                __builtin_amdgcn_global_load_lds(
                    (const __attribute__((address_space(1))) void*)g,
                    (__attribute__((address_space(3))) void*)l, 16, 0, 0);
            }
        }
        __syncthreads();

        bf16x8 a1[4], a2[4], a3[4], b1[4], b2[4], b3[4];
#pragma unroll
        for (int i = 0; i < 4; ++i) {
            int mA = wn + i * 16 + ln;
            int oA = (mA * 4 + (q ^ ((mA >> 1) & 3))) * 16;
            a1[i] = *(const bf16x8*)(lds +     0 + oA);
            a2[i] = *(const bf16x8*)(lds +  8192 + oA);
            a3[i] = *(const bf16x8*)(lds + 16384 + oA);
            int mB = wm + i * 16 + ln;
            int oB = (mB * 4 + (q ^ ((mB >> 1) & 3))) * 16;
            b1[i] = *(const bf16x8*)(lds + 24576 + oB);
            b2[i] = *(const bf16x8*)(lds + 32768 + oB);
            b3[i] = *(const bf16x8*)(lds + 40960 + oB);
        }
#pragma unroll
        for (int i = 0; i < 4; ++i)
#pragma unroll
            for (int j = 0; j < 4; ++j) {
                acc[i][j] = __builtin_amdgcn_mfma_f32_16x16x32_bf16(a1[i], b1[j], acc[i][j], 0, 0, 0);
                acc[i][j] = __builtin_amdgcn_mfma_f32_16x16x32_bf16(a1[i], b2[j], acc[i][j], 0, 0, 0);
                acc[i][j] = __builtin_amdgcn_mfma_f32_16x16x32_bf16(a2[i], b1[j], acc[i][j], 0, 0, 0);
                acc[i][j] = __builtin_amdgcn_mfma_f32_16x16x32_bf16(a2[i], b2[j], acc[i][j], 0, 0, 0);
                acc[i][j] = __builtin_amdgcn_mfma_f32_16x16x32_bf16(a1[i], b3[j], acc[i][j], 0, 0, 0);
                acc[i][j] = __builtin_amdgcn_mfma_f32_16x16x32_bf16(a3[i], b1[j], acc[i][j], 0, 0, 0);
            }
        __syncthreads();
    }

    // epilogue: per-wave LDS transpose (stride 68 u32), full-line stores.
    unsigned* tb = (unsigned*)(lds + w * 4352);
    const int rg = lane >> 4;
    const int c4 = lane & 15;
#pragma unroll
    for (int i = 0; i < 4; ++i) {
#pragma unroll
        for (int j = 0; j < 4; ++j)
#pragma unroll
            for (int r = 0; r < 4; ++r) {
                float v = fmaxf(acc[i][j][r], 0.f);
                unsigned short hi = f2bf(v);
                unsigned short lo = f2bf(v - bf2f(hi));
                tb[(q * 4 + r) * 68 + j * 16 + ln] =
                    (unsigned)hi | ((unsigned)lo << 16);
            }
#pragma unroll
        for (int it = 0; it < 4; ++it) {
            int row = it * 4 + rg;
            uint4 pk = *(const uint4*)&tb[row * 68 + c4 * 4];
            ushort4 h, l;
            h.x = (unsigned short)pk.x; l.x = (unsigned short)(pk.x >> 16);
            h.y = (unsigned short)pk.y; l.y = (unsigned short)(pk.y >> 16);
            h.z = (unsigned short)pk.z; l.z = (unsigned short)(pk.z >> 16);
            h.w = (unsigned short)pk.w; l.w = (unsigned short)(pk.w >> 16);
            size_t off = (size_t)(mBase + wn + i * 16 + row) * 512 + hBase + wm + c4 * 4;
            *(ushort4*)(Fhi + off) = h;
            *(ushort4*)(Flo + off) = l;
        }
    }
}

// ---------------------------------------------------------------------------
// K2: att = F F^T via bf16x3 MFMA — SYMMETRIC (136 upper-triangle pairs).
// VERBATIM R11.
// ---------------------------------------------------------------------------
__global__ __launch_bounds__(256, 2) void att_mfma_sym(
        const unsigned short* __restrict__ Fhi, const unsigned short* __restrict__ Flo,
        const int* __restrict__ mask, float* __restrict__ out) {
    __shared__ char lds[32768];

    const int t = threadIdx.x;
    const int b = blockIdx.z;
    int p = blockIdx.x, ti = 0;
    while (p >= 16 - ti) { p -= 16 - ti; ++ti; }
    const int tj = ti + p;
    const int nBase = ti * 128;
    const int mBase = tj * 128;
    const int w    = t >> 6, lane = t & 63;
    const int q    = lane >> 4, ln = lane & 15;
    const int wn   = (w >> 1) * 64;
    const int wm   = (w & 1) * 64;
    const size_t rowB = (size_t)b * 2048;

    f32x4 acc[4][4] = {};

    for (int kt = 0; kt < 512; kt += 32) {
#pragma unroll
        for (int pp = 0; pp < 4; ++pp) {
            const unsigned short* plane = (pp & 1) ? Flo : Fhi;
            int rbase = (pp < 2) ? nBase : mBase;
#pragma unroll
            for (int r = 0; r < 2; ++r) {
                int chunk = r * 256 + t;
                int row   = chunk >> 2;
                int c     = (chunk & 3) ^ ((row >> 1) & 3);
                const unsigned short* g =
                    plane + ((rowB + rbase + row) * 512 + kt + c * 8);
                char* l = lds + pp * 8192 + chunk * 16;
                __builtin_amdgcn_global_load_lds(
                    (const __attribute__((address_space(1))) void*)g,
                    (__attribute__((address_space(3))) void*)l, 16, 0, 0);
            }
        }
        __syncthreads();

        bf16x8 ah[4], al[4], bh[4], bl[4];
#pragma unroll
        for (int i = 0; i < 4; ++i) {
            int mA = wn + i * 16 + ln;
            int oA = (mA * 4 + (q ^ ((mA >> 1) & 3))) * 16;
            ah[i] = *(const bf16x8*)(lds +     0 + oA);
            al[i] = *(const bf16x8*)(lds +  8192 + oA);
            int mB = wm + i * 16 + ln;
            int oB = (mB * 4 + (q ^ ((mB >> 1) & 3))) * 16;
            bh[i] = *(const bf16x8*)(lds + 16384 + oB);
            bl[i] = *(const bf16x8*)(lds + 24576 + oB);
        }
#pragma unroll
        for (int i = 0; i < 4; ++i)
#pragma unroll
            for (int j = 0; j < 4; ++j) {
                acc[i][j] = __builtin_amdgcn_mfma_f32_16x16x32_bf16(ah[i], bh[j], acc[i][j], 0, 0, 0);
                acc[i][j] = __builtin_amdgcn_mfma_f32_16x16x32_bf16(ah[i], bl[j], acc[i][j], 0, 0, 0);
                acc[i][j] = __builtin_amdgcn_mfma_f32_16x16x32_bf16(al[i], bh[j], acc[i][j], 0, 0, 0);
            }
        __syncthreads();
    }

    const int* mb = mask + b * 2048;
    float* outB = out + (size_t)b * 2048 * 2048;
    int cm[4];
#pragma unroll
    for (int j = 0; j < 4; ++j) cm[j] = mb[mBase + wm + j * 16 + ln];

    float* tb = (float*)(lds + w * 4352);
    const int rg = lane >> 4;
    const int c4 = lane & 15;
    const bool mirror = (ti != tj);
#pragma unroll
    for (int i = 0; i < 4; ++i) {
        int n0 = nBase + wn + i * 16;
        int rmv[4];
#pragma unroll
        for (int r = 0; r < 4; ++r) rmv[r] = mb[n0 + q * 4 + r];
#pragma unroll
        for (int j = 0; j < 4; ++j)
#pragma unroll
            for (int r = 0; r < 4; ++r) {
                float v = ((rmv[r] != 0) & (cm[j] != 0)) ? acc[i][j][r] : NEG_INF;
                tb[(q * 4 + r) * 68 + j * 16 + ln] = v;
            }
#pragma unroll
        for (int it = 0; it < 4; ++it) {
            int row = it * 4 + rg;
            float4 vv = *(const float4*)&tb[row * 68 + c4 * 4];
            *(float4*)(outB + (size_t)(n0 + row) * 2048 + mBase + wm + c4 * 4) = vv;
        }
        if (mirror) {
#pragma unroll
            for (int ps = 0; ps < 4; ++ps) {
                float4 mv;
                mv.x = tb[(ps * 4 + 0) * 68 + lane];
                mv.y = tb[(ps * 4 + 1) * 68 + lane];
                mv.z = tb[(ps * 4 + 2) * 68 + lane];
                mv.w = tb[(ps * 4 + 3) * 68 + lane];
                *(float4*)(outB + (size_t)(mBase + wm + lane) * 2048 + n0 + ps * 4) = mv;
            }
        }
    }
}

// ---------------------------------------------------------------------------
// K3 v3: per-row top-10 via thread-max lower bound.
// M10 = 10th largest of the 256 per-thread maxes  =>  T10 >= M10, so the
// filter "key >= M10" keeps every top-10 element. wave0 then does the exact
// (key, ~idx) top-10 over the survivors (proven purge-butterfly). Same
// selection semantics as v2.
// ---------------------------------------------------------------------------
__global__ __launch_bounds__(256) void topk_rows(float* __restrict__ att) {
    __shared__ float patch[2048];
    __shared__ unsigned long long tmax[256];
    __shared__ unsigned long long cand[512];
    __shared__ int   ncand;
    __shared__ unsigned m10key;
    __shared__ int   top_i[10];
    __shared__ float top_v[10];

    const int t    = threadIdx.x;
    const int lane = t & 63;
    const int w    = t >> 6;
    float* row = att + (size_t)blockIdx.x * 2048;

    float4 a = ((const float4*)row)[2 * t];
    float4 c = ((const float4*)row)[2 * t + 1];
    float v[8] = {a.x, a.y, a.z, a.w, c.x, c.y, c.z, c.w};

    unsigned key[8];
#pragma unroll
    for (int j = 0; j < 8; ++j) key[j] = fkey(v[j]);

    unsigned lmax = key[0];
#pragma unroll
    for (int j = 1; j < 8; ++j) lmax = (key[j] > lmax) ? key[j] : lmax;
    tmax[t] = ((unsigned long long)lmax << 32) | (unsigned)(~(unsigned)t);
    if (t == 0) ncand = 0;
    __syncthreads();

    // ---- wave0: 10th largest of the 256 thread-maxes (4 per lane)
    if (w == 0) {
        unsigned long long k[4];
#pragma unroll
        for (int s = 0; s < 4; ++s) k[s] = tmax[s * 64 + lane];
        unsigned long long lk = k[0]; int li = 0;
#pragma unroll
        for (int s = 1; s < 4; ++s)
            if (k[s] > lk) { lk = k[s]; li = s; }
        unsigned long long m = 0;
        for (int r = 0; r < 10; ++r) {
            m = lk;
#pragma unroll
            for (int off = 1; off < 64; off <<= 1) {
                unsigned long long o = __shfl_xor(m, off, 64);
                m = (o > m) ? o : m;
            }
            if (lk == m) {                      // unique keys: single holder
                k[li] = 0ull;
                lk = k[0]; li = 0;
#pragma unroll
                for (int s = 1; s < 4; ++s)
                    if (k[s] > lk) { lk = k[s]; li = s; }
            }
        }
        if (lane == 0) m10key = (unsigned)(m >> 32);   // 10th largest
    }
    __syncthreads();

    // ---- filter: keep elements with key >= M10 (superset of the top-10)
    const unsigned T = m10key;
    int cnt = 0;
    unsigned long long mine[8];
#pragma unroll
    for (int j = 0; j < 8; ++j)
        if (key[j] >= T)
            mine[cnt++] = ((unsigned long long)key[j] << 32) |
                          (unsigned)(~(unsigned)(t * 8 + j));
    if (cnt) {
        int slot = atomicAdd(&ncand, cnt);
        for (int i = 0; i < cnt; ++i)
            if (slot + i < 512) cand[slot + i] = mine[i];
    }
    __syncthreads();
    const int nc = (ncand < 512) ? ncand : 512;

    // ---- wave0: exact top-10 of the survivors (u64 purge-butterfly)
    if (w == 0) {
        unsigned long long k[8];
#pragma unroll
        for (int s = 0; s < 8; ++s) {
            int idx = s * 64 + lane;
            k[s] = (idx < nc) ? cand[idx] : 0ull;
        }
        unsigned long long lk = k[0]; int li = 0;
#pragma unroll
        for (int s = 1; s < 8; ++s)
            if (k[s] > lk) { lk = k[s]; li = s; }
        for (int r = 0; r < 10; ++r) {
            unsigned long long m = lk;
#pragma unroll
            for (int off = 1; off < 64; off <<= 1) {
                unsigned long long o = __shfl_xor(m, off, 64);
                m = (o > m) ? o : m;
            }
            if (lane == r) {
                unsigned hu = (unsigned)(m >> 32);
                unsigned fu = (hu & 0x80000000u) ? (hu ^ 0x80000000u) : ~hu;
                top_v[r] = __uint_as_float(fu);
                top_i[r] = (int)(~(unsigned)(m & 0xffffffffu));
            }
            if (lk == m) {
                k[li] = 0ull;
                lk = k[0]; li = 0;
#pragma unroll
                for (int s = 1; s < 8; ++s)
                    if (k[s] > lk) { lk = k[s]; li = s; }
            }
        }
    }

    // ---- rewrite row: -1e20 fill + scatter winners (LDS patch)
    float4 ninf4 = make_float4(NEG_INF, NEG_INF, NEG_INF, NEG_INF);
    ((float4*)patch)[2 * t]     = ninf4;
    ((float4*)patch)[2 * t + 1] = ninf4;
    __syncthreads();
    if (t < 10) patch[top_i[t]] = top_v[t];
    __syncthreads();
    ((float4*)row)[2 * t]     = ((float4*)patch)[2 * t];
    ((float4*)row)[2 * t + 1] = ((float4*)patch)[2 * t + 1];
}

// ---------------------------------------------------------------------------
extern "C" void kernel_launch(void* const* d_in, const int* in_sizes, int n_in,
                              void* d_out, int out_size, void* d_ws, size_t ws_size,
                              hipStream_t stream) {
    const float* ctx  = (const float*)d_in[0];   // [8, 2048, 512]
    const float* W    = (const float*)d_in[1];   // [512, 512]
    const int*   mask = (const int*)d_in[2];     // [8, 2048]
    float* out = (float*)d_out;                  // [8, 2048, 2048]

    // bf16 triple-planes for ctx and W live in d_out (dead until att writes)
    const size_t CN = (size_t)16384 * 512;       // 8,388,608
    const size_t WN = (size_t)512 * 512;
    unsigned short* C1 = (unsigned short*)d_out;
    unsigned short* C2 = C1 + CN;
    unsigned short* C3 = C2 + CN;
    unsigned short* W1 = C3 + CN;
    unsigned short* W2 = W1 + WN;
    unsigned short* W3 = W2 + WN;                // ends at 51.9 MB < 134 MB

    unsigned short* Fhi = (unsigned short*)d_ws; // [16384, 512] bf16
    unsigned short* Flo = Fhi + CN;

    dim3 blk(256);
    split3_all<<<dim3(2112), blk, 0, stream>>>(ctx, W, C1, C2, C3, W1, W2, W3);
    fc_mfma6<<<dim3(128, 4), blk, 0, stream>>>(C1, C2, C3, W1, W2, W3, Fhi, Flo);
    att_mfma_sym<<<dim3(136, 1, 8), blk, 0, stream>>>(Fhi, Flo, mask, out);
    topk_rows<<<dim3(16384), blk, 0, stream>>>(out);
}

// Round 13
// 319.323 us; speedup vs baseline: 1.1950x; 1.1950x over previous
//
#include <hip/hip_runtime.h>
#include <hip/hip_bf16.h>

#define NEG_INF -1e20f

typedef __bf16 bf16x8 __attribute__((ext_vector_type(8)));
typedef float  f32x4  __attribute__((ext_vector_type(4)));

__device__ inline unsigned short f2bf(float x) {            // RNE, no NaN inputs
    unsigned u = __float_as_uint(x);
    unsigned r = u + 0x7fffu + ((u >> 16) & 1u);
    return (unsigned short)(r >> 16);
}
__device__ inline float bf2f(unsigned short h) {
    return __uint_as_float((unsigned)h << 16);
}
__device__ inline unsigned fkey(float f) {
    unsigned u = __float_as_uint(f);
    return (u & 0x80000000u) ? ~u : (u | 0x80000000u);
}

// ---------------------------------------------------------------------------
// K0: split ctx AND W into 3 bf16 planes each, one launch. VERBATIM R9.
// ---------------------------------------------------------------------------
__global__ __launch_bounds__(256) void split3_all(
        const float* __restrict__ ctx, const float* __restrict__ W,
        unsigned short* __restrict__ C1, unsigned short* __restrict__ C2,
        unsigned short* __restrict__ C3, unsigned short* __restrict__ W1,
        unsigned short* __restrict__ W2, unsigned short* __restrict__ W3) {
    const int b = blockIdx.x;
    const int t = threadIdx.x;
    const float* src;
    unsigned short *p1, *p2, *p3;
    int base;
    if (b < 2048) { src = ctx; p1 = C1; p2 = C2; p3 = C3; base = b * 1024; }
    else          { src = W;   p1 = W1; p2 = W2; p3 = W3; base = (b - 2048) * 1024; }
#pragma unroll
    for (int it = 0; it < 4; ++it) {
        int i = base + it * 256 + t;
        float4 v = ((const float4*)src)[i];
        ushort4 a, bb, c;
        float r;
        a.x = f2bf(v.x); r = v.x - bf2f(a.x); bb.x = f2bf(r); c.x = f2bf(r - bf2f(bb.x));
        a.y = f2bf(v.y); r = v.y - bf2f(a.y); bb.y = f2bf(r); c.y = f2bf(r - bf2f(bb.y));
        a.z = f2bf(v.z); r = v.z - bf2f(a.z); bb.z = f2bf(r); c.z = f2bf(r - bf2f(bb.z));
        a.w = f2bf(v.w); r = v.w - bf2f(a.w); bb.w = f2bf(r); c.w = f2bf(r - bf2f(bb.w));
        ((ushort4*)p1)[i] = a;
        ((ushort4*)p2)[i] = bb;
        ((ushort4*)p3)[i] = c;
    }
}

// ---------------------------------------------------------------------------
// K1: ctx_fc = relu(context @ W^T) via 6-term bf16 MFMA, 128x128 tile,
// 16x16x32 shape. VERBATIM R9/R11.
// ---------------------------------------------------------------------------
__global__ __launch_bounds__(256, 2) void fc_mfma6(
        const unsigned short* __restrict__ A1, const unsigned short* __restrict__ A2,
        const unsigned short* __restrict__ A3, const unsigned short* __restrict__ B1,
        const unsigned short* __restrict__ B2, const unsigned short* __restrict__ B3,
        unsigned short* __restrict__ Fhi, unsigned short* __restrict__ Flo) {
    __shared__ char lds[49152];

    const int t     = threadIdx.x;
    const int mBase = blockIdx.x * 128;
    const int hBase = blockIdx.y * 128;
    const int w = t >> 6, lane = t & 63;
    const int q = lane >> 4, ln = lane & 15;
    const int wn = (w >> 1) * 64;
    const int wm = (w & 1) * 64;

    f32x4 acc[4][4] = {};

    for (int kt = 0; kt < 512; kt += 32) {
#pragma unroll
        for (int p = 0; p < 3; ++p) {
            const unsigned short* pl = (p == 0) ? A1 : (p == 1) ? A2 : A3;
#pragma unroll
            for (int rr = 0; rr < 2; ++rr) {
                int chunk = rr * 256 + t;
                int row   = chunk >> 2;
                int c     = (chunk & 3) ^ ((row >> 1) & 3);
                const unsigned short* g = pl + ((size_t)(mBase + row) * 512 + kt + c * 8);
                char* l = lds + p * 8192 + chunk * 16;
                __builtin_amdgcn_global_load_lds(
                    (const __attribute__((address_space(1))) void*)g,
                    (__attribute__((address_space(3))) void*)l, 16, 0, 0);
            }
        }
#pragma unroll
        for (int p = 0; p < 3; ++p) {
            const unsigned short* pl = (p == 0) ? B1 : (p == 1) ? B2 : B3;
#pragma unroll
            for (int rr = 0; rr < 2; ++rr) {
                int chunk = rr * 256 + t;
                int row   = chunk >> 2;
                int c     = (chunk & 3) ^ ((row >> 1) & 3);
                const unsigned short* g = pl + ((size_t)(hBase + row) * 512 + kt + c * 8);
                char* l = lds + 24576 + p * 8192 + chunk * 16;
                __builtin_amdgcn_global_load_lds(
                    (const __attribute__((address_space(1))) void*)g,
                    (__attribute__((address_space(3))) void*)l, 16, 0, 0);
            }
        }
        __syncthreads();

        bf16x8 a1[4], a2[4], a3[4], b1[4], b2[4], b3[4];
#pragma unroll
        for (int i = 0; i < 4; ++i) {
            int mA = wn + i * 16 + ln;
            int oA = (mA * 4 + (q ^ ((mA >> 1) & 3))) * 16;
            a1[i] = *(const bf16x8*)(lds +     0 + oA);
            a2[i] = *(const bf16x8*)(lds +  8192 + oA);
            a3[i] = *(const bf16x8*)(lds + 16384 + oA);
            int mB = wm + i * 16 + ln;
            int oB = (mB * 4 + (q ^ ((mB >> 1) & 3))) * 16;
            b1[i] = *(const bf16x8*)(lds + 24576 + oB);
            b2[i] = *(const bf16x8*)(lds + 32768 + oB);
            b3[i] = *(const bf16x8*)(lds + 40960 + oB);
        }
#pragma unroll
        for (int i = 0; i < 4; ++i)
#pragma unroll
            for (int j = 0; j < 4; ++j) {
                acc[i][j] = __builtin_amdgcn_mfma_f32_16x16x32_bf16(a1[i], b1[j], acc[i][j], 0, 0, 0);
                acc[i][j] = __builtin_amdgcn_mfma_f32_16x16x32_bf16(a1[i], b2[j], acc[i][j], 0, 0, 0);
                acc[i][j] = __builtin_amdgcn_mfma_f32_16x16x32_bf16(a2[i], b1[j], acc[i][j], 0, 0, 0);
                acc[i][j] = __builtin_amdgcn_mfma_f32_16x16x32_bf16(a2[i], b2[j], acc[i][j], 0, 0, 0);
                acc[i][j] = __builtin_amdgcn_mfma_f32_16x16x32_bf16(a1[i], b3[j], acc[i][j], 0, 0, 0);
                acc[i][j] = __builtin_amdgcn_mfma_f32_16x16x32_bf16(a3[i], b1[j], acc[i][j], 0, 0, 0);
            }
        __syncthreads();
    }

    unsigned* tb = (unsigned*)(lds + w * 4352);
    const int rg = lane >> 4;
    const int c4 = lane & 15;
#pragma unroll
    for (int i = 0; i < 4; ++i) {
#pragma unroll
        for (int j = 0; j < 4; ++j)
#pragma unroll
            for (int r = 0; r < 4; ++r) {
                float v = fmaxf(acc[i][j][r], 0.f);
                unsigned short hi = f2bf(v);
                unsigned short lo = f2bf(v - bf2f(hi));
                tb[(q * 4 + r) * 68 + j * 16 + ln] =
                    (unsigned)hi | ((unsigned)lo << 16);
            }
#pragma unroll
        for (int it = 0; it < 4; ++it) {
            int row = it * 4 + rg;
            uint4 pk = *(const uint4*)&tb[row * 68 + c4 * 4];
            ushort4 h, l;
            h.x = (unsigned short)pk.x; l.x = (unsigned short)(pk.x >> 16);
            h.y = (unsigned short)pk.y; l.y = (unsigned short)(pk.y >> 16);
            h.z = (unsigned short)pk.z; l.z = (unsigned short)(pk.z >> 16);
            h.w = (unsigned short)pk.w; l.w = (unsigned short)(pk.w >> 16);
            size_t off = (size_t)(mBase + wn + i * 16 + row) * 512 + hBase + wm + c4 * 4;
            *(ushort4*)(Fhi + off) = h;
            *(ushort4*)(Flo + off) = l;
        }
    }
}

// ---------------------------------------------------------------------------
// K2: att = F F^T via bf16x3 MFMA — SYMMETRIC (136 upper-triangle pairs).
// VERBATIM R11.
// ---------------------------------------------------------------------------
__global__ __launch_bounds__(256, 2) void att_mfma_sym(
        const unsigned short* __restrict__ Fhi, const unsigned short* __restrict__ Flo,
        const int* __restrict__ mask, float* __restrict__ out) {
    __shared__ char lds[32768];

    const int t = threadIdx.x;
    const int b = blockIdx.z;
    int p = blockIdx.x, ti = 0;
    while (p >= 16 - ti) { p -= 16 - ti; ++ti; }
    const int tj = ti + p;
    const int nBase = ti * 128;
    const int mBase = tj * 128;
    const int w    = t >> 6, lane = t & 63;
    const int q    = lane >> 4, ln = lane & 15;
    const int wn   = (w >> 1) * 64;
    const int wm   = (w & 1) * 64;
    const size_t rowB = (size_t)b * 2048;

    f32x4 acc[4][4] = {};

    for (int kt = 0; kt < 512; kt += 32) {
#pragma unroll
        for (int pp = 0; pp < 4; ++pp) {
            const unsigned short* plane = (pp & 1) ? Flo : Fhi;
            int rbase = (pp < 2) ? nBase : mBase;
#pragma unroll
            for (int r = 0; r < 2; ++r) {
                int chunk = r * 256 + t;
                int row   = chunk >> 2;
                int c     = (chunk & 3) ^ ((row >> 1) & 3);
                const unsigned short* g =
                    plane + ((rowB + rbase + row) * 512 + kt + c * 8);
                char* l = lds + pp * 8192 + chunk * 16;
                __builtin_amdgcn_global_load_lds(
                    (const __attribute__((address_space(1))) void*)g,
                    (__attribute__((address_space(3))) void*)l, 16, 0, 0);
            }
        }
        __syncthreads();

        bf16x8 ah[4], al[4], bh[4], bl[4];
#pragma unroll
        for (int i = 0; i < 4; ++i) {
            int mA = wn + i * 16 + ln;
            int oA = (mA * 4 + (q ^ ((mA >> 1) & 3))) * 16;
            ah[i] = *(const bf16x8*)(lds +     0 + oA);
            al[i] = *(const bf16x8*)(lds +  8192 + oA);
            int mB = wm + i * 16 + ln;
            int oB = (mB * 4 + (q ^ ((mB >> 1) & 3))) * 16;
            bh[i] = *(const bf16x8*)(lds + 16384 + oB);
            bl[i] = *(const bf16x8*)(lds + 24576 + oB);
        }
#pragma unroll
        for (int i = 0; i < 4; ++i)
#pragma unroll
            for (int j = 0; j < 4; ++j) {
                acc[i][j] = __builtin_amdgcn_mfma_f32_16x16x32_bf16(ah[i], bh[j], acc[i][j], 0, 0, 0);
                acc[i][j] = __builtin_amdgcn_mfma_f32_16x16x32_bf16(ah[i], bl[j], acc[i][j], 0, 0, 0);
                acc[i][j] = __builtin_amdgcn_mfma_f32_16x16x32_bf16(al[i], bh[j], acc[i][j], 0, 0, 0);
            }
        __syncthreads();
    }

    const int* mb = mask + b * 2048;
    float* outB = out + (size_t)b * 2048 * 2048;
    int cm[4];
#pragma unroll
    for (int j = 0; j < 4; ++j) cm[j] = mb[mBase + wm + j * 16 + ln];

    float* tb = (float*)(lds + w * 4352);
    const int rg = lane >> 4;
    const int c4 = lane & 15;
    const bool mirror = (ti != tj);
#pragma unroll
    for (int i = 0; i < 4; ++i) {
        int n0 = nBase + wn + i * 16;
        int rmv[4];
#pragma unroll
        for (int r = 0; r < 4; ++r) rmv[r] = mb[n0 + q * 4 + r];
#pragma unroll
        for (int j = 0; j < 4; ++j)
#pragma unroll
            for (int r = 0; r < 4; ++r) {
                float v = ((rmv[r] != 0) & (cm[j] != 0)) ? acc[i][j][r] : NEG_INF;
                tb[(q * 4 + r) * 68 + j * 16 + ln] = v;
            }
#pragma unroll
        for (int it = 0; it < 4; ++it) {
            int row = it * 4 + rg;
            float4 vv = *(const float4*)&tb[row * 68 + c4 * 4];
            *(float4*)(outB + (size_t)(n0 + row) * 2048 + mBase + wm + c4 * 4) = vv;
        }
        if (mirror) {
#pragma unroll
            for (int ps = 0; ps < 4; ++ps) {
                float4 mv;
                mv.x = tb[(ps * 4 + 0) * 68 + lane];
                mv.y = tb[(ps * 4 + 1) * 68 + lane];
                mv.z = tb[(ps * 4 + 2) * 68 + lane];
                mv.w = tb[(ps * 4 + 3) * 68 + lane];
                *(float4*)(outB + (size_t)(mBase + wm + lane) * 2048 + n0 + ps * 4) = mv;
            }
        }
    }
}

// ---------------------------------------------------------------------------
// K3 v4: ONE WAVE PER ROW, zero barriers. 32 elems/lane, blocked layout
// (idx = lane*32 + jj) so ballot-lowest-lane == lowest global index (same
// tie-break as v2/jax). Per-lane top-2 precompute; O(1) head shift on win;
// taken-bitmask rescan only on a lane's 2nd+ win (rare, execz-skippable).
// 4 independent waves per block, wave-private LDS patch regions.
// ---------------------------------------------------------------------------
__global__ __launch_bounds__(256) void topk_rows(float* __restrict__ att) {
    __shared__ float patch[4][2048];

    const int t    = threadIdx.x;
    const int w    = t >> 6;
    const int lane = t & 63;
    float* row = att + ((size_t)blockIdx.x * 4 + w) * 2048;

    // load 32 elements (blocked): idx = lane*32 + s*4 + j
    unsigned key[32];
#pragma unroll
    for (int s = 0; s < 8; ++s) {
        float4 v = *(const float4*)(row + lane * 32 + s * 4);
        key[s * 4 + 0] = fkey(v.x);
        key[s * 4 + 1] = fkey(v.y);
        key[s * 4 + 2] = fkey(v.z);
        key[s * 4 + 3] = fkey(v.w);
    }

    // per-lane top-2 (strict >, ascending => lowest idx on in-lane ties)
    unsigned h1 = key[0]; int i1 = 0;
#pragma unroll
    for (int j = 1; j < 32; ++j)
        if (key[j] > h1) { h1 = key[j]; i1 = j; }
    unsigned h2 = 0; int i2 = 0;
#pragma unroll
    for (int j = 0; j < 32; ++j) {
        bool ok = (j != i1) && (key[j] > h2);
        h2 = ok ? key[j] : h2;
        i2 = ok ? j : i2;
    }
    bool h2valid = true;
    unsigned taken = 0;

    unsigned myk = 0; int myidx = 0;     // lane r keeps round-r winner
    for (int r = 0; r < 10; ++r) {
        unsigned M = h1;
#pragma unroll
        for (int off = 1; off < 64; off <<= 1) {
            unsigned o = __shfl_xor(M, off, 64);
            M = (o > M) ? o : M;
        }
        unsigned long long ball = __ballot(h1 == M);
        int src  = __ffsll(ball) - 1;            // lowest lane = lowest idx
        int wloc = __shfl(i1, src, 64);
        if (lane == r) { myk = M; myidx = src * 32 + wloc; }
        if (lane == src) {
            taken |= 1u << i1;
            if (h2valid) { h1 = h2; i1 = i2; h2valid = false; }
            else {
                unsigned bh = 0; int bi = 0;
#pragma unroll
                for (int j = 0; j < 32; ++j) {
                    bool ok = (((taken >> j) & 1u) == 0u) && (key[j] > bh);
                    bh = ok ? key[j] : bh;
                    bi = ok ? j : bi;
                }
                h1 = bh; i1 = bi;
            }
        }
    }

    // rewrite row: -1e20 fill + scatter winners (wave-private patch, no bar)
    float* pw = patch[w];
    float4 ninf4 = make_float4(NEG_INF, NEG_INF, NEG_INF, NEG_INF);
#pragma unroll
    for (int s = 0; s < 8; ++s) ((float4*)pw)[s * 64 + lane] = ninf4;
    if (lane < 10) {
        unsigned fu = (myk & 0x80000000u) ? (myk ^ 0x80000000u) : ~myk;
        pw[myidx] = __uint_as_float(fu);
    }
#pragma unroll
    for (int s = 0; s < 8; ++s)
        ((float4*)row)[s * 64 + lane] = ((float4*)pw)[s * 64 + lane];
}

// ---------------------------------------------------------------------------
extern "C" void kernel_launch(void* const* d_in, const int* in_sizes, int n_in,
                              void* d_out, int out_size, void* d_ws, size_t ws_size,
                              hipStream_t stream) {
    const float* ctx  = (const float*)d_in[0];   // [8, 2048, 512]
    const float* W    = (const float*)d_in[1];   // [512, 512]
    const int*   mask = (const int*)d_in[2];     // [8, 2048]
    float* out = (float*)d_out;                  // [8, 2048, 2048]

    const size_t CN = (size_t)16384 * 512;
    const size_t WN = (size_t)512 * 512;
    unsigned short* C1 = (unsigned short*)d_out;
    unsigned short* C2 = C1 + CN;
    unsigned short* C3 = C2 + CN;
    unsigned short* W1 = C3 + CN;
    unsigned short* W2 = W1 + WN;
    unsigned short* W3 = W2 + WN;                // ends at 51.9 MB < 134 MB

    unsigned short* Fhi = (unsigned short*)d_ws;
    unsigned short* Flo = Fhi + CN;

    dim3 blk(256);
    split3_all<<<dim3(2112), blk, 0, stream>>>(ctx, W, C1, C2, C3, W1, W2, W3);
    fc_mfma6<<<dim3(128, 4), blk, 0, stream>>>(C1, C2, C3, W1, W2, W3, Fhi, Flo);
    att_mfma_sym<<<dim3(136, 1, 8), blk, 0, stream>>>(Fhi, Flo, mask, out);
    topk_rows<<<dim3(4096), blk, 0, stream>>>(out);
}

// Round 14
// 300.048 us; speedup vs baseline: 1.2718x; 1.0642x over previous
//
#include <hip/hip_runtime.h>
#include <hip/hip_bf16.h>

#define NEG_INF -1e20f

typedef __bf16 bf16x8 __attribute__((ext_vector_type(8)));
typedef float  f32x4  __attribute__((ext_vector_type(4)));

__device__ inline unsigned short f2bf(float x) {            // RNE, no NaN inputs
    unsigned u = __float_as_uint(x);
    unsigned r = u + 0x7fffu + ((u >> 16) & 1u);
    return (unsigned short)(r >> 16);
}
__device__ inline float bf2f(unsigned short h) {
    return __uint_as_float((unsigned)h << 16);
}
__device__ inline unsigned fkey(float f) {
    unsigned u = __float_as_uint(f);
    return (u & 0x80000000u) ? ~u : (u | 0x80000000u);
}

// ---------------------------------------------------------------------------
// K0: split ctx AND W into 3 bf16 planes each, one launch. VERBATIM R9.
// ---------------------------------------------------------------------------
__global__ __launch_bounds__(256) void split3_all(
        const float* __restrict__ ctx, const float* __restrict__ W,
        unsigned short* __restrict__ C1, unsigned short* __restrict__ C2,
        unsigned short* __restrict__ C3, unsigned short* __restrict__ W1,
        unsigned short* __restrict__ W2, unsigned short* __restrict__ W3) {
    const int b = blockIdx.x;
    const int t = threadIdx.x;
    const float* src;
    unsigned short *p1, *p2, *p3;
    int base;
    if (b < 2048) { src = ctx; p1 = C1; p2 = C2; p3 = C3; base = b * 1024; }
    else          { src = W;   p1 = W1; p2 = W2; p3 = W3; base = (b - 2048) * 1024; }
#pragma unroll
    for (int it = 0; it < 4; ++it) {
        int i = base + it * 256 + t;
        float4 v = ((const float4*)src)[i];
        ushort4 a, bb, c;
        float r;
        a.x = f2bf(v.x); r = v.x - bf2f(a.x); bb.x = f2bf(r); c.x = f2bf(r - bf2f(bb.x));
        a.y = f2bf(v.y); r = v.y - bf2f(a.y); bb.y = f2bf(r); c.y = f2bf(r - bf2f(bb.y));
        a.z = f2bf(v.z); r = v.z - bf2f(a.z); bb.z = f2bf(r); c.z = f2bf(r - bf2f(bb.z));
        a.w = f2bf(v.w); r = v.w - bf2f(a.w); bb.w = f2bf(r); c.w = f2bf(r - bf2f(bb.w));
        ((ushort4*)p1)[i] = a;
        ((ushort4*)p2)[i] = bb;
        ((ushort4*)p3)[i] = c;
    }
}

// ---------------------------------------------------------------------------
// K1: ctx_fc = relu(context @ W^T) via 6-term bf16 MFMA, 128x128 tile,
// 16x16x32 shape. VERBATIM R9/R11.
// ---------------------------------------------------------------------------
__global__ __launch_bounds__(256, 2) void fc_mfma6(
        const unsigned short* __restrict__ A1, const unsigned short* __restrict__ A2,
        const unsigned short* __restrict__ A3, const unsigned short* __restrict__ B1,
        const unsigned short* __restrict__ B2, const unsigned short* __restrict__ B3,
        unsigned short* __restrict__ Fhi, unsigned short* __restrict__ Flo) {
    __shared__ char lds[49152];

    const int t     = threadIdx.x;
    const int mBase = blockIdx.x * 128;
    const int hBase = blockIdx.y * 128;
    const int w = t >> 6, lane = t & 63;
    const int q = lane >> 4, ln = lane & 15;
    const int wn = (w >> 1) * 64;
    const int wm = (w & 1) * 64;

    f32x4 acc[4][4] = {};

    for (int kt = 0; kt < 512; kt += 32) {
#pragma unroll
        for (int p = 0; p < 3; ++p) {
            const unsigned short* pl = (p == 0) ? A1 : (p == 1) ? A2 : A3;
#pragma unroll
            for (int rr = 0; rr < 2; ++rr) {
                int chunk = rr * 256 + t;
                int row   = chunk >> 2;
                int c     = (chunk & 3) ^ ((row >> 1) & 3);
                const unsigned short* g = pl + ((size_t)(mBase + row) * 512 + kt + c * 8);
                char* l = lds + p * 8192 + chunk * 16;
                __builtin_amdgcn_global_load_lds(
                    (const __attribute__((address_space(1))) void*)g,
                    (__attribute__((address_space(3))) void*)l, 16, 0, 0);
            }
        }
#pragma unroll
        for (int p = 0; p < 3; ++p) {
            const unsigned short* pl = (p == 0) ? B1 : (p == 1) ? B2 : B3;
#pragma unroll
            for (int rr = 0; rr < 2; ++rr) {
                int chunk = rr * 256 + t;
                int row   = chunk >> 2;
                int c     = (chunk & 3) ^ ((row >> 1) & 3);
                const unsigned short* g = pl + ((size_t)(hBase + row) * 512 + kt + c * 8);
                char* l = lds + 24576 + p * 8192 + chunk * 16;
                __builtin_amdgcn_global_load_lds(
                    (const __attribute__((address_space(1))) void*)g,
                    (__attribute__((address_space(3))) void*)l, 16, 0, 0);
            }
        }
        __syncthreads();

        bf16x8 a1[4], a2[4], a3[4], b1[4], b2[4], b3[4];
#pragma unroll
        for (int i = 0; i < 4; ++i) {
            int mA = wn + i * 16 + ln;
            int oA = (mA * 4 + (q ^ ((mA >> 1) & 3))) * 16;
            a1[i] = *(const bf16x8*)(lds +     0 + oA);
            a2[i] = *(const bf16x8*)(lds +  8192 + oA);
            a3[i] = *(const bf16x8*)(lds + 16384 + oA);
            int mB = wm + i * 16 + ln;
            int oB = (mB * 4 + (q ^ ((mB >> 1) & 3))) * 16;
            b1[i] = *(const bf16x8*)(lds + 24576 + oB);
            b2[i] = *(const bf16x8*)(lds + 32768 + oB);
            b3[i] = *(const bf16x8*)(lds + 40960 + oB);
        }
#pragma unroll
        for (int i = 0; i < 4; ++i)
#pragma unroll
            for (int j = 0; j < 4; ++j) {
                acc[i][j] = __builtin_amdgcn_mfma_f32_16x16x32_bf16(a1[i], b1[j], acc[i][j], 0, 0, 0);
                acc[i][j] = __builtin_amdgcn_mfma_f32_16x16x32_bf16(a1[i], b2[j], acc[i][j], 0, 0, 0);
                acc[i][j] = __builtin_amdgcn_mfma_f32_16x16x32_bf16(a2[i], b1[j], acc[i][j], 0, 0, 0);
                acc[i][j] = __builtin_amdgcn_mfma_f32_16x16x32_bf16(a2[i], b2[j], acc[i][j], 0, 0, 0);
                acc[i][j] = __builtin_amdgcn_mfma_f32_16x16x32_bf16(a1[i], b3[j], acc[i][j], 0, 0, 0);
                acc[i][j] = __builtin_amdgcn_mfma_f32_16x16x32_bf16(a3[i], b1[j], acc[i][j], 0, 0, 0);
            }
        __syncthreads();
    }

    unsigned* tb = (unsigned*)(lds + w * 4352);
    const int rg = lane >> 4;
    const int c4 = lane & 15;
#pragma unroll
    for (int i = 0; i < 4; ++i) {
#pragma unroll
        for (int j = 0; j < 4; ++j)
#pragma unroll
            for (int r = 0; r < 4; ++r) {
                float v = fmaxf(acc[i][j][r], 0.f);
                unsigned short hi = f2bf(v);
                unsigned short lo = f2bf(v - bf2f(hi));
                tb[(q * 4 + r) * 68 + j * 16 + ln] =
                    (unsigned)hi | ((unsigned)lo << 16);
            }
#pragma unroll
        for (int it = 0; it < 4; ++it) {
            int row = it * 4 + rg;
            uint4 pk = *(const uint4*)&tb[row * 68 + c4 * 4];
            ushort4 h, l;
            h.x = (unsigned short)pk.x; l.x = (unsigned short)(pk.x >> 16);
            h.y = (unsigned short)pk.y; l.y = (unsigned short)(pk.y >> 16);
            h.z = (unsigned short)pk.z; l.z = (unsigned short)(pk.z >> 16);
            h.w = (unsigned short)pk.w; l.w = (unsigned short)(pk.w >> 16);
            size_t off = (size_t)(mBase + wn + i * 16 + row) * 512 + hBase + wm + c4 * 4;
            *(ushort4*)(Fhi + off) = h;
            *(ushort4*)(Flo + off) = l;
        }
    }
}

// ---------------------------------------------------------------------------
// K2: att = F F^T via bf16x3 MFMA — SYMMETRIC (136 upper-triangle pairs).
// R11 body; grid flattened to 1088 with batch = blockIdx.x & 7 so the
// round-robin block->XCD placement pins each batch's working set (4.2 MB
// Fhi/Flo slice) to one XCD's L2. Output bit-identical to R11/R13.
// ---------------------------------------------------------------------------
__global__ __launch_bounds__(256, 2) void att_mfma_sym(
        const unsigned short* __restrict__ Fhi, const unsigned short* __restrict__ Flo,
        const int* __restrict__ mask, float* __restrict__ out) {
    __shared__ char lds[32768];

    const int t = threadIdx.x;
    const int b = blockIdx.x & 7;        // XCD-pinned batch
    int p = blockIdx.x >> 3, ti = 0;     // pair 0..135
    while (p >= 16 - ti) { p -= 16 - ti; ++ti; }
    const int tj = ti + p;
    const int nBase = ti * 128;
    const int mBase = tj * 128;
    const int w    = t >> 6, lane = t & 63;
    const int q    = lane >> 4, ln = lane & 15;
    const int wn   = (w >> 1) * 64;
    const int wm   = (w & 1) * 64;
    const size_t rowB = (size_t)b * 2048;

    f32x4 acc[4][4] = {};

    for (int kt = 0; kt < 512; kt += 32) {
#pragma unroll
        for (int pp = 0; pp < 4; ++pp) {
            const unsigned short* plane = (pp & 1) ? Flo : Fhi;
            int rbase = (pp < 2) ? nBase : mBase;
#pragma unroll
            for (int r = 0; r < 2; ++r) {
                int chunk = r * 256 + t;
                int row   = chunk >> 2;
                int c     = (chunk & 3) ^ ((row >> 1) & 3);
                const unsigned short* g =
                    plane + ((rowB + rbase + row) * 512 + kt + c * 8);
                char* l = lds + pp * 8192 + chunk * 16;
                __builtin_amdgcn_global_load_lds(
                    (const __attribute__((address_space(1))) void*)g,
                    (__attribute__((address_space(3))) void*)l, 16, 0, 0);
            }
        }
        __syncthreads();

        bf16x8 ah[4], al[4], bh[4], bl[4];
#pragma unroll
        for (int i = 0; i < 4; ++i) {
            int mA = wn + i * 16 + ln;
            int oA = (mA * 4 + (q ^ ((mA >> 1) & 3))) * 16;
            ah[i] = *(const bf16x8*)(lds +     0 + oA);
            al[i] = *(const bf16x8*)(lds +  8192 + oA);
            int mB = wm + i * 16 + ln;
            int oB = (mB * 4 + (q ^ ((mB >> 1) & 3))) * 16;
            bh[i] = *(const bf16x8*)(lds + 16384 + oB);
            bl[i] = *(const bf16x8*)(lds + 24576 + oB);
        }
#pragma unroll
        for (int i = 0; i < 4; ++i)
#pragma unroll
            for (int j = 0; j < 4; ++j) {
                acc[i][j] = __builtin_amdgcn_mfma_f32_16x16x32_bf16(ah[i], bh[j], acc[i][j], 0, 0, 0);
                acc[i][j] = __builtin_amdgcn_mfma_f32_16x16x32_bf16(ah[i], bl[j], acc[i][j], 0, 0, 0);
                acc[i][j] = __builtin_amdgcn_mfma_f32_16x16x32_bf16(al[i], bh[j], acc[i][j], 0, 0, 0);
            }
        __syncthreads();
    }

    const int* mb = mask + b * 2048;
    float* outB = out + (size_t)b * 2048 * 2048;
    int cm[4];
#pragma unroll
    for (int j = 0; j < 4; ++j) cm[j] = mb[mBase + wm + j * 16 + ln];

    float* tb = (float*)(lds + w * 4352);
    const int rg = lane >> 4;
    const int c4 = lane & 15;
    const bool mirror = (ti != tj);
#pragma unroll
    for (int i = 0; i < 4; ++i) {
        int n0 = nBase + wn + i * 16;
        int rmv[4];
#pragma unroll
        for (int r = 0; r < 4; ++r) rmv[r] = mb[n0 + q * 4 + r];
#pragma unroll
        for (int j = 0; j < 4; ++j)
#pragma unroll
            for (int r = 0; r < 4; ++r) {
                float v = ((rmv[r] != 0) & (cm[j] != 0)) ? acc[i][j][r] : NEG_INF;
                tb[(q * 4 + r) * 68 + j * 16 + ln] = v;
            }
#pragma unroll
        for (int it = 0; it < 4; ++it) {
            int row = it * 4 + rg;
            float4 vv = *(const float4*)&tb[row * 68 + c4 * 4];
            *(float4*)(outB + (size_t)(n0 + row) * 2048 + mBase + wm + c4 * 4) = vv;
        }
        if (mirror) {
#pragma unroll
            for (int ps = 0; ps < 4; ++ps) {
                float4 mv;
                mv.x = tb[(ps * 4 + 0) * 68 + lane];
                mv.y = tb[(ps * 4 + 1) * 68 + lane];
                mv.z = tb[(ps * 4 + 2) * 68 + lane];
                mv.w = tb[(ps * 4 + 3) * 68 + lane];
                *(float4*)(outB + (size_t)(mBase + wm + lane) * 2048 + n0 + ps * 4) = mv;
            }
        }
    }
}

// ---------------------------------------------------------------------------
// K3 v4: ONE WAVE PER ROW, zero barriers. VERBATIM R13.
// ---------------------------------------------------------------------------
__global__ __launch_bounds__(256) void topk_rows(float* __restrict__ att) {
    __shared__ float patch[4][2048];

    const int t    = threadIdx.x;
    const int w    = t >> 6;
    const int lane = t & 63;
    float* row = att + ((size_t)blockIdx.x * 4 + w) * 2048;

    unsigned key[32];
#pragma unroll
    for (int s = 0; s < 8; ++s) {
        float4 v = *(const float4*)(row + lane * 32 + s * 4);
        key[s * 4 + 0] = fkey(v.x);
        key[s * 4 + 1] = fkey(v.y);
        key[s * 4 + 2] = fkey(v.z);
        key[s * 4 + 3] = fkey(v.w);
    }

    unsigned h1 = key[0]; int i1 = 0;
#pragma unroll
    for (int j = 1; j < 32; ++j)
        if (key[j] > h1) { h1 = key[j]; i1 = j; }
    unsigned h2 = 0; int i2 = 0;
#pragma unroll
    for (int j = 0; j < 32; ++j) {
        bool ok = (j != i1) && (key[j] > h2);
        h2 = ok ? key[j] : h2;
        i2 = ok ? j : i2;
    }
    bool h2valid = true;
    unsigned taken = 0;

    unsigned myk = 0; int myidx = 0;
    for (int r = 0; r < 10; ++r) {
        unsigned M = h1;
#pragma unroll
        for (int off = 1; off < 64; off <<= 1) {
            unsigned o = __shfl_xor(M, off, 64);
            M = (o > M) ? o : M;
        }
        unsigned long long ball = __ballot(h1 == M);
        int src  = __ffsll(ball) - 1;
        int wloc = __shfl(i1, src, 64);
        if (lane == r) { myk = M; myidx = src * 32 + wloc; }
        if (lane == src) {
            taken |= 1u << i1;
            if (h2valid) { h1 = h2; i1 = i2; h2valid = false; }
            else {
                unsigned bh = 0; int bi = 0;
#pragma unroll
                for (int j = 0; j < 32; ++j) {
                    bool ok = (((taken >> j) & 1u) == 0u) && (key[j] > bh);
                    bh = ok ? key[j] : bh;
                    bi = ok ? j : bi;
                }
                h1 = bh; i1 = bi;
            }
        }
    }

    float* pw = patch[w];
    float4 ninf4 = make_float4(NEG_INF, NEG_INF, NEG_INF, NEG_INF);
#pragma unroll
    for (int s = 0; s < 8; ++s) ((float4*)pw)[s * 64 + lane] = ninf4;
    if (lane < 10) {
        unsigned fu = (myk & 0x80000000u) ? (myk ^ 0x80000000u) : ~myk;
        pw[myidx] = __uint_as_float(fu);
    }
#pragma unroll
    for (int s = 0; s < 8; ++s)
        ((float4*)row)[s * 64 + lane] = ((float4*)pw)[s * 64 + lane];
}

// ---------------------------------------------------------------------------
extern "C" void kernel_launch(void* const* d_in, const int* in_sizes, int n_in,
                              void* d_out, int out_size, void* d_ws, size_t ws_size,
                              hipStream_t stream) {
    const float* ctx  = (const float*)d_in[0];   // [8, 2048, 512]
    const float* W    = (const float*)d_in[1];   // [512, 512]
    const int*   mask = (const int*)d_in[2];     // [8, 2048]
    float* out = (float*)d_out;                  // [8, 2048, 2048]

    const size_t CN = (size_t)16384 * 512;
    const size_t WN = (size_t)512 * 512;
    unsigned short* C1 = (unsigned short*)d_out;
    unsigned short* C2 = C1 + CN;
    unsigned short* C3 = C2 + CN;
    unsigned short* W1 = C3 + CN;
    unsigned short* W2 = W1 + WN;
    unsigned short* W3 = W2 + WN;                // ends at 51.9 MB < 134 MB

    unsigned short* Fhi = (unsigned short*)d_ws;
    unsigned short* Flo = Fhi + CN;

    dim3 blk(256);
    split3_all<<<dim3(2112), blk, 0, stream>>>(ctx, W, C1, C2, C3, W1, W2, W3);
    fc_mfma6<<<dim3(128, 4), blk, 0, stream>>>(C1, C2, C3, W1, W2, W3, Fhi, Flo);
    att_mfma_sym<<<dim3(1088), blk, 0, stream>>>(Fhi, Flo, mask, out);
    topk_rows<<<dim3(4096), blk, 0, stream>>>(out);
}